// Round 1
// baseline (1741.740 us; speedup 1.0000x reference)
//
#include <hip/hip_runtime.h>

// LSTMBaseline: B=2048, T=512, H=128, 4H=512, FF=64, OUT=2 ; fp32 in/out.
// R10: kill the scratch spill (WRITE_SIZE was 10.8 MB vs 16 KB logical output
// => ~80 B/thread spilled, reloaded from L2 every timestep).
//  (1) per-thread constants (biases, wih0 row) evicted to LDS tables; biases
//      folded into MFMA acc init (acc starts at bias, not 0).
//  (2) weights pre-scaled by log2e (2*log2e for g-gate) at frag load: sigm/tanh
//      lose their leading multiply.
//  (3) gbuf split into gA/gB (per layer): removes WAR serialization between
//      cell0 reads and MM1 writes.
//  (4) dual accumulators accA/accB share one a0 ds_read per kt: MM0/MM1 MFMA
//      chains interleave instead of serializing through a reused acc.
//  (5) __launch_bounds__(NT,2) pins the 256-reg / 2-wave-per-SIMD point.
// Weights stay as bf16 B-frags laundered into AGPRs (R8).

#define TT 512
#define HH 128
#define FFD 64
#define BB 8
#define NT 512   // threads per block = 8 waves
#define HP 136   // padded LDS row stride (ushort); 272B = 16B-aligned rows

typedef __attribute__((ext_vector_type(8))) short short8;
typedef __attribute__((ext_vector_type(4))) float f32x4;

__device__ __forceinline__ unsigned short f2b(float f) {
    unsigned int i = __builtin_bit_cast(unsigned int, f);
    i += 0x7FFFu + ((i >> 16) & 1u);   // RNE
    return (unsigned short)(i >> 16);
}
__device__ __forceinline__ float b2f(unsigned short u) {
    return __builtin_bit_cast(float, ((unsigned int)u) << 16);
}
__device__ __forceinline__ float fexp2(float x) {
#if __has_builtin(__builtin_amdgcn_exp2f)
    return __builtin_amdgcn_exp2f(x);     // v_exp_f32
#else
    return exp2f(x);
#endif
}
__device__ __forceinline__ float frcp(float x) {
#if __has_builtin(__builtin_amdgcn_rcpf)
    return __builtin_amdgcn_rcpf(x);      // v_rcp_f32
#else
    return 1.0f / x;
#endif
}
// pre-scaled activations: y already multiplied by log2e (sigm) / 2*log2e (tanh)
__device__ __forceinline__ float sigm_s(float y) {
    return frcp(1.0f + fexp2(-y));
}
__device__ __forceinline__ float tanh_s(float y) {
    return 1.0f - 2.0f * frcp(1.0f + fexp2(y));
}
// natural-domain tanh (for cell state c)
__device__ __forceinline__ float tanh_c(float x) {
    return 1.0f - 2.0f * frcp(1.0f + fexp2(2.8853900817779268f * x));
}
// 8 consecutive fp32 -> bf16 short8 fragment, scaled
__device__ __forceinline__ short8 ldfrag(const float* p, unsigned idx, float s) {
    const float4* q = reinterpret_cast<const float4*>(p + idx);
    float4 a = q[0], b = q[1];
    short8 r;
    r[0] = (short)f2b(a.x * s); r[1] = (short)f2b(a.y * s);
    r[2] = (short)f2b(a.z * s); r[3] = (short)f2b(a.w * s);
    r[4] = (short)f2b(b.x * s); r[5] = (short)f2b(b.y * s);
    r[6] = (short)f2b(b.z * s); r[7] = (short)f2b(b.w * s);
    return r;
}

#define L2E  1.4426950408889634f
#define L2E2 2.8853900817779268f

__global__ __launch_bounds__(NT, 2) void lstm2_fused(
    const float* __restrict__ hr,
    const float* __restrict__ glu,
    const float* __restrict__ wih0,
    const float* __restrict__ whh0,
    const float* __restrict__ bih0,
    const float* __restrict__ bhh0,
    const float* __restrict__ wih1,
    const float* __restrict__ whh1,
    const float* __restrict__ bih1,
    const float* __restrict__ bhh1,
    const float* __restrict__ w1,
    const float* __restrict__ b1,
    const float* __restrict__ w2,
    const float* __restrict__ b2,
    float* __restrict__ out)
{
    // h(t) lives in buffer t&1. Rows 8..15 stay zero (MFMA M=16 padding).
    __shared__ __align__(16) unsigned short h0b[2][16][HP];
    __shared__ __align__(16) unsigned short h1b[2][16][HP];
    __shared__ float gA[8][4][8][16];   // layer-0 gates  [wave][gate][row][col]
    __shared__ float gB[8][4][8][16];   // layer-1 gates
    __shared__ float hrs[BB][TT + 4];
    __shared__ float glus[BB][TT + 4];
    __shared__ float bs0[512];          // scaled (bih0+bhh0)
    __shared__ float bs1[512];          // scaled (bih1+bhh1)
    __shared__ float wab[512][2];       // scaled wih0 rows (hr, glu weights)
    __shared__ float hid[BB][FFD];

    const int tid  = threadIdx.x;
    const int lane = tid & 63;
    const int wv   = tid >> 6;        // 0..7
    const int nrow = lane & 15;       // MFMA m (A) / n (B) index
    const int kg   = lane >> 4;       // MFMA k-group 0..3
    const int b0   = blockIdx.x * BB;

    // ---- init LDS ----
    {
        unsigned short* p0 = &h0b[0][0][0];
        unsigned short* p1 = &h1b[0][0][0];
        for (int i = tid; i < 2 * 16 * HP; i += NT) { p0[i] = 0; p1[i] = 0; }
        for (int i = tid; i < BB * TT; i += NT) {   // coalesced over t
            int row = i >> 9;
            int t   = i & (TT - 1);
            unsigned gi = (unsigned)(b0 + row) * TT + t;
            hrs[row][t]  = hr[gi];
            glus[row][t] = glu[gi];
        }
        // per-column constants, pre-scaled (one col per thread, NT==512)
        {
            int c  = tid;
            int g  = c >> 7;
            float s = (g == 2) ? L2E2 : L2E;
            bs0[c] = (bih0[c] + bhh0[c]) * s;
            bs1[c] = (bih1[c] + bhh1[c]) * s;
            wab[c][0] = wih0[2 * c] * s;
            wab[c][1] = wih0[2 * c + 1] * s;
        }
    }

    // ---- weight fragments: wave w owns gate cols {128g + 16w + nrow} ----
    // B-frag 16x16x32: lane(n=lane&15, q=lane>>4) holds B[k=32kt+8q+e][n]=W[col][k]
    short8 W0f[4][4];   // [g][kt] whh0, K=128
    short8 W1f[4][8];   // [g][kt] wih1 (kt<4) / whh1 (kt>=4), K=256
#pragma unroll
    for (int g = 0; g < 4; g++) {
        const float s = (g == 2) ? L2E2 : L2E;
        unsigned gc = (unsigned)(128 * g + 16 * wv + nrow);
#pragma unroll
        for (int kt = 0; kt < 4; kt++) {
            unsigned off = gc * HH + kt * 32 + kg * 8;
            W0f[g][kt]     = ldfrag(whh0, off, s);
            W1f[g][kt]     = ldfrag(wih1, off, s);
            W1f[g][kt + 4] = ldfrag(whh1, off, s);
        }
    }
    // pin loop-invariant weights to AGPRs (R8: eliminates scratch spill)
#pragma unroll
    for (int g = 0; g < 4; g++) {
#pragma unroll
        for (int kt = 0; kt < 4; kt++) { asm volatile("" : "+a"(W0f[g][kt])); }
#pragma unroll
        for (int kt = 0; kt < 8; kt++) { asm volatile("" : "+a"(W1f[g][kt])); }
    }

    // ---- per-thread cell units: col j = 16wv+jj; rows rlo and rlo+4 ----
    const int jj  = lane & 15;
    const int rlo = lane >> 4;        // 0..3
    const int j   = 16 * wv + jj;
    float c0[2] = {0.f, 0.f};
    float c1[2] = {0.f, 0.f};
    __syncthreads();

    // ---- recurrence: ONE barrier per iteration ----
    for (int it = 0; it <= TT; it++) {
        const int p = (it + 1) & 1;   // buffer holding h(it-1)
        const int q = it & 1;         // buffer for h0(it); holds h1(it-2)
        const bool doA = (it < TT);
        const bool doB = (it > 0);

        f32x4 accA[4], accB[4];
        // acc init = bias (pre-scaled); column = nrow == jj for this lane
        if (doA) {
#pragma unroll
            for (int g = 0; g < 4; g++) {
                float b = bs0[128 * g + j];
                f32x4 z = {b, b, b, b};
                accA[g] = z;
            }
        }
        if (doB) {
#pragma unroll
            for (int g = 0; g < 4; g++) {
                float b = bs1[128 * g + j];
                f32x4 z = {b, b, b, b};
                accB[g] = z;
            }
        }

        // shared-A MFMA: one a0 frag load per kt feeds BOTH MM0 and MM1
#pragma unroll
        for (int kt = 0; kt < 4; kt++) {
            short8 a0 = *reinterpret_cast<const short8*>(&h0b[p][nrow][kt * 32 + kg * 8]);
            if (doA) {
#pragma unroll
                for (int g = 0; g < 4; g++)
                    accA[g] = __builtin_amdgcn_mfma_f32_16x16x32_bf16(a0, W0f[g][kt], accA[g], 0, 0, 0);
            }
            if (doB) {
#pragma unroll
                for (int g = 0; g < 4; g++)
                    accB[g] = __builtin_amdgcn_mfma_f32_16x16x32_bf16(a0, W1f[g][kt], accB[g], 0, 0, 0);
            }
        }
        // layer-0 gates out (accA dead after this)
        if (doA && kg < 2) {
#pragma unroll
            for (int g = 0; g < 4; g++)
#pragma unroll
                for (int rr = 0; rr < 4; rr++)
                    gA[wv][g][4 * kg + rr][nrow] = accA[g][rr];
        }
        if (doB) {
#pragma unroll
            for (int kt = 0; kt < 4; kt++) {
                short8 a1 = *reinterpret_cast<const short8*>(&h1b[q][nrow][kt * 32 + kg * 8]);
#pragma unroll
                for (int g = 0; g < 4; g++)
                    accB[g] = __builtin_amdgcn_mfma_f32_16x16x32_bf16(a1, W1f[g][kt + 4], accB[g], 0, 0, 0);
            }
            if (kg < 2) {
#pragma unroll
                for (int g = 0; g < 4; g++)
#pragma unroll
                    for (int rr = 0; rr < 4; rr++)
                        gB[wv][g][4 * kg + rr][nrow] = accB[g][rr];
            }
        }

        // cell0(it): gA already contains bias + whh0*h0; add x-projection
        if (doA) {
            float wax[4], wbx[4];
#pragma unroll
            for (int g = 0; g < 4; g++) {
                float2 t = *reinterpret_cast<const float2*>(&wab[128 * g + j][0]);
                wax[g] = t.x; wbx[g] = t.y;
            }
#pragma unroll
            for (int rep = 0; rep < 2; rep++) {
                int r = rlo + 4 * rep;
                float xh = hrs[r][it];
                float xg = glus[r][it];
                float pi = gA[wv][0][r][jj] + xh * wax[0] + xg * wbx[0];
                float pf = gA[wv][1][r][jj] + xh * wax[1] + xg * wbx[1];
                float pg = gA[wv][2][r][jj] + xh * wax[2] + xg * wbx[2];
                float po = gA[wv][3][r][jj] + xh * wax[3] + xg * wbx[3];
                float ig = sigm_s(pi), fg = sigm_s(pf), gg = tanh_s(pg), og = sigm_s(po);
                float c = fg * c0[rep] + ig * gg;
                c0[rep] = c;
                h0b[q][r][j] = f2b(og * tanh_c(c));   // h0(it) -> buf q
            }
        }
        // cell1(it-1): gB is the complete pre-activation (bias folded in)
        if (doB) {
#pragma unroll
            for (int rep = 0; rep < 2; rep++) {
                int r = rlo + 4 * rep;
                float pi = gB[wv][0][r][jj];
                float pf = gB[wv][1][r][jj];
                float pg = gB[wv][2][r][jj];
                float po = gB[wv][3][r][jj];
                float ig = sigm_s(pi), fg = sigm_s(pf), gg = tanh_s(pg), og = sigm_s(po);
                float c = fg * c1[rep] + ig * gg;
                c1[rep] = c;
                h1b[p][r][j] = f2b(og * tanh_c(c));
            }
        }
        __syncthreads();
    }

    // ---- head: h1 final = h1(TT-1) in h1b[(TT-1)&1] = h1b[1] ----
    {
        int r  = tid >> 6;      // 0..7
        int ff = tid & 63;
        float a2 = 0.f;
        for (int k = 0; k < HH; k++)
            a2 += b2f(h1b[1][r][k]) * w1[(unsigned)ff * HH + k];
        hid[r][ff] = fmaxf(a2 + b1[ff], 0.f);
    }
    __syncthreads();
    if (tid < 16) {
        int r = tid >> 1;
        int o = tid & 1;
        float a2 = b2[o];
        for (int k = 0; k < FFD; k++)
            a2 += hid[r][k] * w2[(unsigned)o * FFD + k];
        out[(b0 + r) * 2 + o] = a2;    // fp32 output
    }
}

extern "C" void kernel_launch(void* const* d_in, const int* in_sizes, int n_in,
                              void* d_out, int out_size, void* d_ws, size_t ws_size,
                              hipStream_t stream) {
    const float* hr   = (const float*)d_in[0];
    const float* glu  = (const float*)d_in[1];
    const float* wih0 = (const float*)d_in[2];
    const float* whh0 = (const float*)d_in[3];
    const float* bih0 = (const float*)d_in[4];
    const float* bhh0 = (const float*)d_in[5];
    const float* wih1 = (const float*)d_in[6];
    const float* whh1 = (const float*)d_in[7];
    const float* bih1 = (const float*)d_in[8];
    const float* bhh1 = (const float*)d_in[9];
    const float* w1   = (const float*)d_in[10];
    const float* b1   = (const float*)d_in[11];
    const float* w2   = (const float*)d_in[12];
    const float* b2   = (const float*)d_in[13];
    float* out = (float*)d_out;

    lstm2_fused<<<dim3(2048 / BB), dim3(NT), 0, stream>>>(
        hr, glu, wih0, whh0, bih0, bhh0, wih1, whh1, bih1, bhh1,
        w1, b1, w2, b2, out);
}